// Round 4
// baseline (563.593 us; speedup 1.0000x reference)
//
#include <hip/hip_runtime.h>

// Unpooling (2x2, stride 2, pad 0), B=32 C=64 H=W=112 -> Ho=Wo=224.
// fm fp32, switches int32, out fp32 (verified round 2: passed, absmax=0).
//
// Gather/expand inversion: input (hi,wi) owns disjoint 2x2 output block at
// (2hi,2wi); switches in [0,4) picks the cell (0:(0,0) 1:(0,1) 2:(1,0)
// 3:(1,1)); other cells zero. Every output written exactly once -> no
// atomics, no zero-init.
//
// R3 -> R4: same plan as R3 (4 elems/thread, 16B loads, nontemporal), but
// with clang ext_vector types -- __builtin_nontemporal_* rejects
// HIP_vector_type classes (R3 compile failure). Mandatory traffic 617 MB
// -> ~98us floor at 6.3 TB/s.

#define BB 32
#define CC 64
#define HH 112
#define WW 112
#define HO 224
#define WO 224

typedef float __attribute__((ext_vector_type(4))) vf4;
typedef int   __attribute__((ext_vector_type(4))) vi4;

__global__ __launch_bounds__(256) void unpool_kernel(
    const float* __restrict__ fm,
    const int*   __restrict__ sw,
    float*       __restrict__ out)
{
    const int tid = blockIdx.x * blockDim.x + threadIdx.x;
    // total threads = B*C*H*(W/4) = 6,422,528 ; grid exact, no bounds check
    const int chunk = tid % (WW / 4);        // 4-wide chunk within input row (28/row)
    const int rowid = tid / (WW / 4);        // global input row index
    const int hi    = rowid % HH;
    const int plane = rowid / HH;            // b*C + c

    const int in_idx = tid * 4;              // flat input index (contiguous)
    const vf4 f = __builtin_nontemporal_load((const vf4*)(fm + in_idx));
    const vi4 s = __builtin_nontemporal_load((const vi4*)(sw + in_idx));

    vf4 e0, e1, o0, o1;                      // even-row [0:4),[4:8) ; odd-row same
    e0.x = (s.x == 0) ? f.x : 0.0f;  e0.y = (s.x == 1) ? f.x : 0.0f;
    e0.z = (s.y == 0) ? f.y : 0.0f;  e0.w = (s.y == 1) ? f.y : 0.0f;
    e1.x = (s.z == 0) ? f.z : 0.0f;  e1.y = (s.z == 1) ? f.z : 0.0f;
    e1.z = (s.w == 0) ? f.w : 0.0f;  e1.w = (s.w == 1) ? f.w : 0.0f;
    o0.x = (s.x == 2) ? f.x : 0.0f;  o0.y = (s.x == 3) ? f.x : 0.0f;
    o0.z = (s.y == 2) ? f.y : 0.0f;  o0.w = (s.y == 3) ? f.y : 0.0f;
    o1.x = (s.z == 2) ? f.z : 0.0f;  o1.y = (s.z == 3) ? f.z : 0.0f;
    o1.z = (s.w == 2) ? f.w : 0.0f;  o1.w = (s.w == 3) ? f.w : 0.0f;

    const int out_base = plane * (HO * WO) + (hi * 2) * WO + chunk * 8;  // < 2^31
    vf4* pe = (vf4*)(out + out_base);        // row 2*hi,   16B aligned
    vf4* po = (vf4*)(out + out_base + WO);   // row 2*hi+1, 16B aligned
    __builtin_nontemporal_store(e0, pe);
    __builtin_nontemporal_store(e1, pe + 1);
    __builtin_nontemporal_store(o0, po);
    __builtin_nontemporal_store(o1, po + 1);
}

extern "C" void kernel_launch(void* const* d_in, const int* in_sizes, int n_in,
                              void* d_out, int out_size, void* d_ws, size_t ws_size,
                              hipStream_t stream) {
    const float* fm  = (const float*)d_in[0];   // fp32 feature_map
    const int*   sw  = (const int*)d_in[1];     // int32 switches
    float*       out = (float*)d_out;           // fp32 output

    const int total_threads = BB * CC * HH * (WW / 4);   // 6,422,528
    const int block = 256;
    const int grid  = total_threads / block;             // 25,088 exactly
    unpool_kernel<<<grid, block, 0, stream>>>(fm, sw, out);
}